// Round 4
// baseline (607.064 us; speedup 1.0000x reference)
//
#include <hip/hip_runtime.h>
#include <math.h>

// Round 4: pipelined 4-wave attention (reg-staged, 2 barriers/tile, wave-local
// softmax) + bf16-MFMA projection. oT now bf16.
//
// Pipeline:
//   gn_stats  -> per-(b,g) mean/rstd
//   fold_k    -> ascale, bias2 (Q pre-scaled 1/16), wb = bf16(qkv_w), pwb = bf16(proj_w)
//   xt_k      -> xbT[b][n][c] = bf16(x * ascale)
//   qkv_mfma  -> qT[b][n][c], kT[b][n][c], vN[b][c][n] (bf16)
//   attn_mfma -> oTb[b][n][c] bf16 (flash, fp32 online softmax, bf16 MFMA)
//   proj_mfma -> out = x + proj_w @ o + proj_b (bf16 MFMA, fp32 epilogue)

#define BATCH 4
#define CH 256
#define NSP 4096
#define NGRP 8
#define CPG 32

typedef __attribute__((ext_vector_type(8))) short bf16x8;   // 8 bf16 = 4 VGPRs
typedef __attribute__((ext_vector_type(4))) float f32x4;    // MFMA 16x16 accumulator

__device__ __forceinline__ unsigned short f2bf(float f) {
  union { float f; unsigned u; } v; v.f = f;
  unsigned r = v.u + 0x7FFF + ((v.u >> 16) & 1);   // RNE
  return (unsigned short)(r >> 16);
}

// ---------------- kernel 1: GroupNorm statistics ----------------
__global__ __launch_bounds__(256) void gn_stats_k(const float* __restrict__ x,
                                                  float* __restrict__ stats) {
  const int bg = blockIdx.x;
  const float4* p = (const float4*)(x + (size_t)bg * CPG * NSP);
  const int t = threadIdx.x;
  float s1 = 0.f, s2 = 0.f;
  for (int i = t; i < CPG * NSP / 4; i += 256) {
    float4 v = p[i];
    s1 += v.x + v.y + v.z + v.w;
    s2 += v.x * v.x + v.y * v.y + v.z * v.z + v.w * v.w;
  }
  __shared__ float r1[256], r2[256];
  r1[t] = s1; r2[t] = s2;
  __syncthreads();
  for (int off = 128; off > 0; off >>= 1) {
    if (t < off) { r1[t] += r1[t + off]; r2[t] += r2[t + off]; }
    __syncthreads();
  }
  if (t == 0) {
    const float inv = 1.f / (float)(CPG * NSP);
    const float mean = r1[0] * inv;
    const float var = r2[0] * inv - mean * mean;
    stats[bg * 2] = mean;
    stats[bg * 2 + 1] = rsqrtf(var + 1e-5f);
  }
}

// ------- kernel 2: fold GN affine; convert qkv_w and proj_w to bf16 -------
__global__ __launch_bounds__(256) void fold_k(const float* __restrict__ gn_w,
                                              const float* __restrict__ gn_b,
                                              const float* __restrict__ qkv_w,
                                              const float* __restrict__ qkv_b,
                                              const float* __restrict__ proj_w,
                                              const float* __restrict__ stats,
                                              float* __restrict__ ascale,
                                              float* __restrict__ bias2,
                                              unsigned short* __restrict__ wb,
                                              unsigned short* __restrict__ pwb) {
  const int b = blockIdx.x;   // 4 blocks, 256 threads
  const int t = threadIdx.x;
  __shared__ float bb[CH];
  {
    const int c = t;
    const int g = c / CPG;
    const float mean = stats[(b * NGRP + g) * 2];
    const float rstd = stats[(b * NGRP + g) * 2 + 1];
    const float a = rstd * gn_w[c];
    ascale[b * CH + c] = a;
    bb[c] = gn_b[c] - mean * a;
  }
  __syncthreads();
  for (int o = t; o < 3 * CH; o += 256) {
    const float* wrow = qkv_w + (size_t)o * CH;
    float acc = qkv_b[o];
    for (int c = 0; c < CH; ++c) acc += wrow[c] * bb[c];
    if (o < CH) acc *= 0.0625f;
    bias2[b * 3 * CH + o] = acc;
  }
  // qkv weight -> bf16 (each block does 192 rows)
  for (int idx = t; idx < 192 * CH; idx += 256) {
    const int row = b * 192 + (idx >> 8);
    const int c = idx & 255;
    float w = qkv_w[(size_t)row * CH + c];
    if (row < CH) w *= 0.0625f;
    wb[(size_t)row * CH + c] = f2bf(w);
  }
  // proj weight -> bf16 (each block does 64 rows)
  for (int idx = t; idx < 64 * CH; idx += 256) {
    const int row = b * 64 + (idx >> 8);
    const int c = idx & 255;
    pwb[(size_t)row * CH + c] = f2bf(proj_w[(size_t)row * CH + c]);
  }
}

// ------- kernel 3: x -> xbT[b][n][c] = bf16(x * ascale)  (transpose) -------
__global__ __launch_bounds__(256) void xt_k(const float* __restrict__ x,
                                            const float* __restrict__ ascale,
                                            unsigned short* __restrict__ xbT) {
  const int b = blockIdx.z, cb = blockIdx.y * 64, nb = blockIdx.x * 64;
  const int t = threadIdx.x;
  __shared__ float Ls[64][68];
  for (int i = 0; i < 4; ++i) {
    const int idx = t + i * 256;
    const int c = idx >> 4, n4 = (idx & 15) << 2;
    const float a = ascale[b * CH + cb + c];
    const float4 v = *(const float4*)(x + ((size_t)(b * CH + cb + c)) * NSP + nb + n4);
    Ls[c][n4] = v.x * a; Ls[c][n4 + 1] = v.y * a;
    Ls[c][n4 + 2] = v.z * a; Ls[c][n4 + 3] = v.w * a;
  }
  __syncthreads();
  {
    const int n = t >> 2, cg = (t & 3) << 4;
    unsigned int pk[8];
#pragma unroll
    for (int j = 0; j < 8; ++j) {
      const unsigned short l16 = f2bf(Ls[cg + 2 * j][n]);
      const unsigned short h16 = f2bf(Ls[cg + 2 * j + 1][n]);
      pk[j] = (unsigned)l16 | ((unsigned)h16 << 16);
    }
    unsigned short* dst = xbT + ((size_t)(b * NSP) + nb + n) * CH + cb + cg;
    *(uint4*)dst = *(uint4*)&pk[0];
    *(uint4*)(dst + 8) = *(uint4*)&pk[4];
  }
}

// ------- kernel 4: QKV GEMM, bf16 MFMA -------
__global__ __launch_bounds__(256) void qkv_mfma_k(const unsigned short* __restrict__ wb,
                                                  const unsigned short* __restrict__ xbT,
                                                  const float* __restrict__ bias2,
                                                  unsigned short* __restrict__ qT,
                                                  unsigned short* __restrict__ kT,
                                                  unsigned short* __restrict__ vN) {
  const int b = blockIdx.z, ob = blockIdx.y * 64, nb = blockIdx.x * 64;
  const int t = threadIdx.x;
  __shared__ short Ws[64][264];
  __shared__ short Xs[64][264];
  for (int i = 0; i < 8; ++i) {
    const int idx = t + i * 256;
    const int row = idx >> 5, u = (idx & 31) << 3;
    *(float4*)&Ws[row][u] = *(const float4*)(wb + ((size_t)(ob + row)) * CH + u);
    *(float4*)&Xs[row][u] = *(const float4*)(xbT + ((size_t)(b * NSP) + nb + row) * CH + u);
  }
  __syncthreads();
  const int lane = t & 63, wave = t >> 6, lo = lane & 15, hi = lane >> 4;
  const f32x4 zero = {0.f, 0.f, 0.f, 0.f};
  f32x4 acc[4] = {zero, zero, zero, zero};
#pragma unroll
  for (int ks = 0; ks < 8; ++ks) {
    const bf16x8 a = *(const bf16x8*)&Ws[wave * 16 + lo][ks * 32 + hi * 8];
#pragma unroll
    for (int nt = 0; nt < 4; ++nt) {
      const bf16x8 xv = *(const bf16x8*)&Xs[nt * 16 + lo][ks * 32 + hi * 8];
      acc[nt] = __builtin_amdgcn_mfma_f32_16x16x32_bf16(a, xv, acc[nt], 0, 0, 0);
    }
  }
#pragma unroll
  for (int nt = 0; nt < 4; ++nt) {
#pragma unroll
    for (int r = 0; r < 4; ++r) {
      const int o = ob + wave * 16 + hi * 4 + r;
      const int n = nb + nt * 16 + lo;
      const float v = acc[nt][r] + bias2[b * 3 * CH + o];
      if (o < CH)            qT[((size_t)(b * NSP) + n) * CH + o] = f2bf(v);
      else if (o < 2 * CH)   kT[((size_t)(b * NSP) + n) * CH + (o - CH)] = f2bf(v);
      else                   vN[((size_t)(b * CH) + (o - 2 * CH)) * NSP + n] = f2bf(v);
    }
  }
}

// ------- kernel 5: flash attention v2 — 4 waves, reg-staged pipeline -------
// Wave w owns q rows [qb+16w, qb+16w+16); computes full 64-m tile itself.
// Per tile: issue K(next) -> QK -> softmax (wave-local) -> issue V(next) -> PV
//           -> barrier -> ds_write next tile -> barrier.
__global__ __launch_bounds__(256, 1) void attn_mfma_k(const unsigned short* __restrict__ qT,
                                                      const unsigned short* __restrict__ kT,
                                                      const unsigned short* __restrict__ vN,
                                                      unsigned short* __restrict__ oTb) {
  const int b = blockIdx.y;
  const int qb = blockIdx.x * 64;
  const int t = threadIdx.x;
  const int wid = t >> 6, lane = t & 63, lo = lane & 15, hi = lane >> 4;

  __shared__ __align__(16) char smem[79872];
  short (*Kt)[264] = (short(*)[264])(smem);                 // [64][264]  33792 B
  short (*Vs)[72]  = (short(*)[72])(smem + 33792);          // [256][72]  36864 B
  short* Psw = (short*)(smem + 33792 + 36864) + wid * 16 * 72;  // per-wave [16][72]

  const unsigned short* kbase = kT + (size_t)b * NSP * CH;
  const unsigned short* vbase = vN + (size_t)b * CH * NSP;

  // Q fragments in registers: 16 q rows, full C (8 k-steps)
  const int qrow = qb + wid * 16 + lo;
  bf16x8 qreg[8];
#pragma unroll
  for (int ks = 0; ks < 8; ++ks)
    qreg[ks] = *(const bf16x8*)(qT + ((size_t)(b * NSP) + qrow) * CH + ks * 32 + hi * 8);

  float mrun[4] = {-INFINITY, -INFINITY, -INFINITY, -INFINITY};
  float lrun[4] = {0.f, 0.f, 0.f, 0.f};
  const f32x4 zero = {0.f, 0.f, 0.f, 0.f};
  f32x4 oacc[16];
#pragma unroll
  for (int i = 0; i < 16; ++i) oacc[i] = zero;

  float4 kreg[8], vreg[8];
  // prologue: stage tile 0
#pragma unroll
  for (int i = 0; i < 8; ++i) {
    const int idx = t + i * 256;
    const int krow = idx >> 5, ku = (idx & 31) << 3;      // K: [64][256]
    const int vrow = idx >> 3, vu = (idx & 7) << 3;       // V: [256][64]
    kreg[i] = *(const float4*)(kbase + ((size_t)(0 + krow)) * CH + ku);
    vreg[i] = *(const float4*)(vbase + (size_t)vrow * NSP + 0 + vu);
  }
#pragma unroll
  for (int i = 0; i < 8; ++i) {
    const int idx = t + i * 256;
    const int krow = idx >> 5, ku = (idx & 31) << 3;
    const int vrow = idx >> 3, vu = (idx & 7) << 3;
    *(float4*)&Kt[krow][ku] = kreg[i];
    *(float4*)&Vs[vrow][vu] = vreg[i];
  }
  __syncthreads();

  for (int kt = 0; kt < NSP; kt += 64) {
    const bool notlast = (kt + 64 < NSP);
    if (notlast) {
#pragma unroll
      for (int i = 0; i < 8; ++i) {
        const int idx = t + i * 256;
        const int krow = idx >> 5, ku = (idx & 31) << 3;
        kreg[i] = *(const float4*)(kbase + ((size_t)(kt + 64 + krow)) * CH + ku);
      }
    }
    // ---- S = Q K^T : 16q x 64m ----
    f32x4 s[4] = {zero, zero, zero, zero};
#pragma unroll
    for (int ks = 0; ks < 8; ++ks) {
#pragma unroll
      for (int mt = 0; mt < 4; ++mt) {
        const bf16x8 kv = *(const bf16x8*)&Kt[mt * 16 + lo][ks * 32 + hi * 8];
        s[mt] = __builtin_amdgcn_mfma_f32_16x16x32_bf16(qreg[ks], kv, s[mt], 0, 0, 0);
      }
    }
    // ---- wave-local online softmax (rows r=hi*4+r spread over lo) ----
    float alpha[4];
#pragma unroll
    for (int r = 0; r < 4; ++r) {
      float mx = fmaxf(fmaxf(s[0][r], s[1][r]), fmaxf(s[2][r], s[3][r]));
      mx = fmaxf(mx, __shfl_xor(mx, 1));
      mx = fmaxf(mx, __shfl_xor(mx, 2));
      mx = fmaxf(mx, __shfl_xor(mx, 4));
      mx = fmaxf(mx, __shfl_xor(mx, 8));
      const float mm = fmaxf(mx, mrun[r]);
      alpha[r] = __expf(mrun[r] - mm);
      mrun[r] = mm;
      float p0 = __expf(s[0][r] - mm);
      float p1 = __expf(s[1][r] - mm);
      float p2 = __expf(s[2][r] - mm);
      float p3 = __expf(s[3][r] - mm);
      Psw[(hi * 4 + r) * 72 + 0 * 16 + lo] = (short)f2bf(p0);
      Psw[(hi * 4 + r) * 72 + 1 * 16 + lo] = (short)f2bf(p1);
      Psw[(hi * 4 + r) * 72 + 2 * 16 + lo] = (short)f2bf(p2);
      Psw[(hi * 4 + r) * 72 + 3 * 16 + lo] = (short)f2bf(p3);
      float ps = p0 + p1 + p2 + p3;
      ps += __shfl_xor(ps, 1);
      ps += __shfl_xor(ps, 2);
      ps += __shfl_xor(ps, 4);
      ps += __shfl_xor(ps, 8);
      lrun[r] = lrun[r] * alpha[r] + ps;
    }
    if (notlast) {
#pragma unroll
      for (int i = 0; i < 8; ++i) {
        const int idx = t + i * 256;
        const int vrow = idx >> 3, vu = (idx & 7) << 3;
        vreg[i] = *(const float4*)(vbase + (size_t)vrow * NSP + kt + 64 + vu);
      }
    }
    // ---- O = O*alpha + P V^T  (full 256 c) ----
#pragma unroll
    for (int ct = 0; ct < 16; ++ct) {
#pragma unroll
      for (int r = 0; r < 4; ++r) oacc[ct][r] *= alpha[r];
    }
    const bf16x8 pa0 = *(const bf16x8*)&Psw[lo * 72 + hi * 8];
    const bf16x8 pa1 = *(const bf16x8*)&Psw[lo * 72 + 32 + hi * 8];
#pragma unroll
    for (int ct = 0; ct < 16; ++ct) {
      const bf16x8 v0 = *(const bf16x8*)&Vs[ct * 16 + lo][hi * 8];
      oacc[ct] = __builtin_amdgcn_mfma_f32_16x16x32_bf16(pa0, v0, oacc[ct], 0, 0, 0);
      const bf16x8 v1 = *(const bf16x8*)&Vs[ct * 16 + lo][32 + hi * 8];
      oacc[ct] = __builtin_amdgcn_mfma_f32_16x16x32_bf16(pa1, v1, oacc[ct], 0, 0, 0);
    }
    if (notlast) {
      __syncthreads();   // all waves done reading Kt/Vs
#pragma unroll
      for (int i = 0; i < 8; ++i) {
        const int idx = t + i * 256;
        const int krow = idx >> 5, ku = (idx & 31) << 3;
        const int vrow = idx >> 3, vu = (idx & 7) << 3;
        *(float4*)&Kt[krow][ku] = kreg[i];
        *(float4*)&Vs[vrow][vu] = vreg[i];
      }
      __syncthreads();   // stage visible
    }
  }

  // ---- epilogue: normalize, LDS-transpose, coalesced bf16 store ----
  float linv[4];
#pragma unroll
  for (int r = 0; r < 4; ++r) linv[r] = 1.f / lrun[r];
  __syncthreads();   // everyone done with Kt/Vs
  float* Tr = ((float*)smem) + wid * (16 * 260);   // per-wave [16][260]
#pragma unroll
  for (int ct = 0; ct < 16; ++ct) {
#pragma unroll
    for (int r = 0; r < 4; ++r)
      Tr[(hi * 4 + r) * 260 + ct * 16 + lo] = oacc[ct][r] * linv[r];
  }
  const int qrl = lane >> 2;            // 0..15
  const int c0 = (lane & 3) << 6;       // 0,64,128,192
  const int n = qb + wid * 16 + qrl;
  unsigned short* dst = oTb + ((size_t)(b * NSP) + n) * CH + c0;
#pragma unroll
  for (int jj = 0; jj < 8; ++jj) {
    const float4 a = *(const float4*)&Tr[qrl * 260 + c0 + jj * 8];
    const float4 c2 = *(const float4*)&Tr[qrl * 260 + c0 + jj * 8 + 4];
    uint4 pk;
    pk.x = (unsigned)f2bf(a.x) | ((unsigned)f2bf(a.y) << 16);
    pk.y = (unsigned)f2bf(a.z) | ((unsigned)f2bf(a.w) << 16);
    pk.z = (unsigned)f2bf(c2.x) | ((unsigned)f2bf(c2.y) << 16);
    pk.w = (unsigned)f2bf(c2.z) | ((unsigned)f2bf(c2.w) << 16);
    *(uint4*)(dst + jj * 8) = pk;
  }
}

// ------- kernel 6: projection + residual, bf16 MFMA -------
__global__ __launch_bounds__(256) void proj_mfma_k(const unsigned short* __restrict__ pwb,
                                                   const unsigned short* __restrict__ oTb,
                                                   const float* __restrict__ proj_b,
                                                   const float* __restrict__ x,
                                                   float* __restrict__ out) {
  const int b = blockIdx.z, ob = blockIdx.y * 64, nb = blockIdx.x * 64;
  const int t = threadIdx.x;
  __shared__ short Ws[64][264];
  __shared__ short Os[64][264];
  for (int i = 0; i < 8; ++i) {
    const int idx = t + i * 256;
    const int row = idx >> 5, u = (idx & 31) << 3;
    *(float4*)&Ws[row][u] = *(const float4*)(pwb + ((size_t)(ob + row)) * CH + u);
    *(float4*)&Os[row][u] = *(const float4*)(oTb + ((size_t)(b * NSP) + nb + row) * CH + u);
  }
  __syncthreads();
  const int lane = t & 63, wave = t >> 6, lo = lane & 15, hi = lane >> 4;
  const f32x4 zero = {0.f, 0.f, 0.f, 0.f};
  f32x4 acc[4] = {zero, zero, zero, zero};
#pragma unroll
  for (int ks = 0; ks < 8; ++ks) {
    const bf16x8 a = *(const bf16x8*)&Ws[wave * 16 + lo][ks * 32 + hi * 8];
#pragma unroll
    for (int nt = 0; nt < 4; ++nt) {
      const bf16x8 ov = *(const bf16x8*)&Os[nt * 16 + lo][ks * 32 + hi * 8];
      acc[nt] = __builtin_amdgcn_mfma_f32_16x16x32_bf16(a, ov, acc[nt], 0, 0, 0);
    }
  }
#pragma unroll
  for (int nt = 0; nt < 4; ++nt) {
#pragma unroll
    for (int r = 0; r < 4; ++r) {
      const int o = ob + wave * 16 + hi * 4 + r;
      const int n = nb + nt * 16 + lo;
      const size_t off = ((size_t)(b * CH + o)) * NSP + n;
      out[off] = acc[nt][r] + proj_b[o] + x[off];
    }
  }
}

extern "C" void kernel_launch(void* const* d_in, const int* in_sizes, int n_in,
                              void* d_out, int out_size, void* d_ws, size_t ws_size,
                              hipStream_t stream) {
  const float* x      = (const float*)d_in[0];
  const float* gn_w   = (const float*)d_in[1];
  const float* gn_b   = (const float*)d_in[2];
  const float* qkv_w  = (const float*)d_in[3];
  const float* qkv_b  = (const float*)d_in[4];
  const float* proj_w = (const float*)d_in[5];
  const float* proj_b = (const float*)d_in[6];
  float* out = (float*)d_out;

  char* w = (char*)d_ws;
  unsigned short* qT  = (unsigned short*)w; w += (size_t)BATCH * NSP * CH * 2;
  unsigned short* kT  = (unsigned short*)w; w += (size_t)BATCH * NSP * CH * 2;
  unsigned short* vN  = (unsigned short*)w; w += (size_t)BATCH * NSP * CH * 2;
  unsigned short* xbT = (unsigned short*)w; w += (size_t)BATCH * NSP * CH * 2;
  unsigned short* oTb = (unsigned short*)w; w += (size_t)BATCH * NSP * CH * 2;
  unsigned short* wb  = (unsigned short*)w; w += (size_t)3 * CH * CH * 2;
  unsigned short* pwb = (unsigned short*)w; w += (size_t)CH * CH * 2;
  float* stats  = (float*)w; w += 64 * 4;
  float* ascale = (float*)w; w += BATCH * CH * 4;
  float* bias2  = (float*)w; w += BATCH * 3 * CH * 4;

  gn_stats_k<<<BATCH * NGRP, 256, 0, stream>>>(x, stats);
  fold_k<<<BATCH, 256, 0, stream>>>(gn_w, gn_b, qkv_w, qkv_b, proj_w, stats,
                                    ascale, bias2, wb, pwb);
  xt_k<<<dim3(NSP / 64, CH / 64, BATCH), 256, 0, stream>>>(x, ascale, xbT);
  qkv_mfma_k<<<dim3(NSP / 64, 3 * CH / 64, BATCH), 256, 0, stream>>>(wb, xbT, bias2, qT, kT, vN);
  attn_mfma_k<<<dim3(NSP / 64, BATCH), 256, 0, stream>>>(qT, kT, vN, oTb);
  proj_mfma_k<<<dim3(NSP / 64, CH / 64, BATCH), 256, 0, stream>>>(pwb, oTb, proj_b, x, out);
}

// Round 6
// 330.718 us; speedup vs baseline: 1.8356x; 1.8356x over previous
//
#include <hip/hip_runtime.h>
#include <math.h>

// Round 6 (= round 5 resubmit; bench never ran): attn v3 — global_load_lds
// double-buffered K/V (no reg staging, no spills), wave-local online softmax
// with end-merge of m-halves, 1 barrier/tile, XOR-swizzled LDS (pre-swizzled
// global source), XCD-aware block swizzle, defer-max, setprio. gn_stats split
// into 2 phases. qkv/xt/proj as round 4. Only change vs r5: __any() gate.

#define BATCH 4
#define CH 256
#define NSP 4096
#define NGRP 8
#define CPG 32

typedef __attribute__((ext_vector_type(8))) short bf16x8;
typedef __attribute__((ext_vector_type(4))) float f32x4;

__device__ __forceinline__ unsigned short f2bf(float f) {
  union { float f; unsigned u; } v; v.f = f;
  unsigned r = v.u + 0x7FFF + ((v.u >> 16) & 1);   // RNE
  return (unsigned short)(r >> 16);
}

__device__ __forceinline__ void gload_lds16(const void* g, void* l) {
  __builtin_amdgcn_global_load_lds(
      (const __attribute__((address_space(1))) unsigned int*)g,
      (__attribute__((address_space(3))) unsigned int*)l, 16, 0, 0);
}

// ---------------- kernel 1a: GroupNorm partial sums (256 blocks) ----------------
__global__ __launch_bounds__(256) void gn_part_k(const float* __restrict__ x,
                                                 float* __restrict__ gpart) {
  const int bid = blockIdx.x;          // bg*8 + slice
  const int bg = bid >> 3, sl = bid & 7;
  const float4* p = (const float4*)(x + (size_t)bg * CPG * NSP + (size_t)sl * (CPG * NSP / 8));
  const int t = threadIdx.x;
  float s1 = 0.f, s2 = 0.f;
#pragma unroll
  for (int i = 0; i < 16; ++i) {
    float4 v = p[t + i * 256];
    s1 += v.x + v.y + v.z + v.w;
    s2 += v.x * v.x + v.y * v.y + v.z * v.z + v.w * v.w;
  }
  __shared__ float r1[256], r2[256];
  r1[t] = s1; r2[t] = s2;
  __syncthreads();
  for (int off = 128; off > 0; off >>= 1) {
    if (t < off) { r1[t] += r1[t + off]; r2[t] += r2[t + off]; }
    __syncthreads();
  }
  if (t == 0) { gpart[bid * 2] = r1[0]; gpart[bid * 2 + 1] = r2[0]; }
}

// ------- kernel 2: finalize stats, fold GN affine, convert weights -------
__global__ __launch_bounds__(256) void fold_k(const float* __restrict__ gn_w,
                                              const float* __restrict__ gn_b,
                                              const float* __restrict__ qkv_w,
                                              const float* __restrict__ qkv_b,
                                              const float* __restrict__ proj_w,
                                              const float* __restrict__ gpart,
                                              float* __restrict__ ascale,
                                              float* __restrict__ bias2,
                                              unsigned short* __restrict__ wb,
                                              unsigned short* __restrict__ pwb) {
  const int b = blockIdx.x;
  const int t = threadIdx.x;
  __shared__ float bb[CH];
  {
    const int c = t;
    const int g = c >> 5;
    float s1 = 0.f, s2 = 0.f;
#pragma unroll
    for (int s = 0; s < 8; ++s) {
      s1 += gpart[((b * NGRP + g) * 8 + s) * 2];
      s2 += gpart[((b * NGRP + g) * 8 + s) * 2 + 1];
    }
    const float inv = 1.f / (float)(CPG * NSP);
    const float mean = s1 * inv;
    const float var = s2 * inv - mean * mean;
    const float rstd = rsqrtf(var + 1e-5f);
    const float a = rstd * gn_w[c];
    ascale[b * CH + c] = a;
    bb[c] = gn_b[c] - mean * a;
  }
  __syncthreads();
  for (int o = t; o < 3 * CH; o += 256) {
    const float* wrow = qkv_w + (size_t)o * CH;
    float acc = qkv_b[o];
    for (int c = 0; c < CH; ++c) acc += wrow[c] * bb[c];
    if (o < CH) acc *= 0.0625f;
    bias2[b * 3 * CH + o] = acc;
  }
  for (int idx = t; idx < 192 * CH; idx += 256) {
    const int row = b * 192 + (idx >> 8);
    const int c = idx & 255;
    float w = qkv_w[(size_t)row * CH + c];
    if (row < CH) w *= 0.0625f;
    wb[(size_t)row * CH + c] = f2bf(w);
  }
  for (int idx = t; idx < 64 * CH; idx += 256) {
    const int row = b * 64 + (idx >> 8);
    const int c = idx & 255;
    pwb[(size_t)row * CH + c] = f2bf(proj_w[(size_t)row * CH + c]);
  }
}

// ------- kernel 3: x -> xbT[b][n][c] = bf16(x * ascale)  (transpose) -------
__global__ __launch_bounds__(256) void xt_k(const float* __restrict__ x,
                                            const float* __restrict__ ascale,
                                            unsigned short* __restrict__ xbT) {
  const int b = blockIdx.z, cb = blockIdx.y * 64, nb = blockIdx.x * 64;
  const int t = threadIdx.x;
  __shared__ float Ls[64][68];
  for (int i = 0; i < 4; ++i) {
    const int idx = t + i * 256;
    const int c = idx >> 4, n4 = (idx & 15) << 2;
    const float a = ascale[b * CH + cb + c];
    const float4 v = *(const float4*)(x + ((size_t)(b * CH + cb + c)) * NSP + nb + n4);
    Ls[c][n4] = v.x * a; Ls[c][n4 + 1] = v.y * a;
    Ls[c][n4 + 2] = v.z * a; Ls[c][n4 + 3] = v.w * a;
  }
  __syncthreads();
  {
    const int n = t >> 2, cg = (t & 3) << 4;
    unsigned int pk[8];
#pragma unroll
    for (int j = 0; j < 8; ++j) {
      const unsigned short l16 = f2bf(Ls[cg + 2 * j][n]);
      const unsigned short h16 = f2bf(Ls[cg + 2 * j + 1][n]);
      pk[j] = (unsigned)l16 | ((unsigned)h16 << 16);
    }
    unsigned short* dst = xbT + ((size_t)(b * NSP) + nb + n) * CH + cb + cg;
    *(uint4*)dst = *(uint4*)&pk[0];
    *(uint4*)(dst + 8) = *(uint4*)&pk[4];
  }
}

// ------- kernel 4: QKV GEMM, bf16 MFMA -------
__global__ __launch_bounds__(256) void qkv_mfma_k(const unsigned short* __restrict__ wb,
                                                  const unsigned short* __restrict__ xbT,
                                                  const float* __restrict__ bias2,
                                                  unsigned short* __restrict__ qT,
                                                  unsigned short* __restrict__ kT,
                                                  unsigned short* __restrict__ vN) {
  const int b = blockIdx.z, ob = blockIdx.y * 64, nb = blockIdx.x * 64;
  const int t = threadIdx.x;
  __shared__ short Ws[64][264];
  __shared__ short Xs[64][264];
  for (int i = 0; i < 8; ++i) {
    const int idx = t + i * 256;
    const int row = idx >> 5, u = (idx & 31) << 3;
    *(float4*)&Ws[row][u] = *(const float4*)(wb + ((size_t)(ob + row)) * CH + u);
    *(float4*)&Xs[row][u] = *(const float4*)(xbT + ((size_t)(b * NSP) + nb + row) * CH + u);
  }
  __syncthreads();
  const int lane = t & 63, wave = t >> 6, lo = lane & 15, hi = lane >> 4;
  const f32x4 zero = {0.f, 0.f, 0.f, 0.f};
  f32x4 acc[4] = {zero, zero, zero, zero};
#pragma unroll
  for (int ks = 0; ks < 8; ++ks) {
    const bf16x8 a = *(const bf16x8*)&Ws[wave * 16 + lo][ks * 32 + hi * 8];
#pragma unroll
    for (int nt = 0; nt < 4; ++nt) {
      const bf16x8 xv = *(const bf16x8*)&Xs[nt * 16 + lo][ks * 32 + hi * 8];
      acc[nt] = __builtin_amdgcn_mfma_f32_16x16x32_bf16(a, xv, acc[nt], 0, 0, 0);
    }
  }
#pragma unroll
  for (int nt = 0; nt < 4; ++nt) {
#pragma unroll
    for (int r = 0; r < 4; ++r) {
      const int o = ob + wave * 16 + hi * 4 + r;
      const int n = nb + nt * 16 + lo;
      const float v = acc[nt][r] + bias2[b * 3 * CH + o];
      if (o < CH)            qT[((size_t)(b * NSP) + n) * CH + o] = f2bf(v);
      else if (o < 2 * CH)   kT[((size_t)(b * NSP) + n) * CH + (o - CH)] = f2bf(v);
      else                   vN[((size_t)(b * CH) + (o - 2 * CH)) * NSP + n] = f2bf(v);
    }
  }
}

// ------- kernel 5: flash attention v3 -------
// 512 thr / 8 waves = 4 pairs; wave (pair,wip) owns 16 q x m-half wip, with its
// OWN running (m,l,O over full 256 c). Halves merged once in epilogue.
// K/V double-buffered via global_load_lds; XOR-swizzle via pre-swizzled source.
__global__ __launch_bounds__(512, 2) void attn_mfma_k(const unsigned short* __restrict__ qT,
                                                      const unsigned short* __restrict__ kT,
                                                      const unsigned short* __restrict__ vN,
                                                      unsigned short* __restrict__ oTb) {
  // XCD swizzle: logical L = xcd*32 + slot ; batch = L>>6 -> 2 XCDs per batch
  const int bid = blockIdx.x;
  const int L = (bid & 7) * 32 + (bid >> 3);
  const int b = L >> 6;
  const int qb = (L & 63) * 64;

  const int t = threadIdx.x;
  const int wid = t >> 6, lane = t & 63, lo = lane & 15, hi = lane >> 4;
  const int pair = wid >> 1, wip = wid & 1;

  // smem map: [0,65536) K dbuf [2][64][256]s ; [65536,131072) V dbuf [2][256][64]s
  //           [131072,141312) Psw [8][16][40]s ; [141312,142336) sM/sL
  __shared__ __align__(16) char smem[142336];
  short* Psw = (short*)(smem + 131072) + wid * 16 * 40;
  float* sM = (float*)(smem + 141312);
  float* sL = sM + 128;

  const unsigned short* kTb = kT + (size_t)b * NSP * CH;
  const unsigned short* vNb = vN + (size_t)b * CH * NSP;

  // Q fragments: rows = pair's 16 q, full C
  const int qrow = qb + pair * 16 + lo;
  bf16x8 qreg[8];
#pragma unroll
  for (int ks = 0; ks < 8; ++ks)
    qreg[ks] = *(const bf16x8*)(qT + ((size_t)(b * NSP) + qrow) * CH + ks * 32 + hi * 8);

  float mrun[4] = {-INFINITY, -INFINITY, -INFINITY, -INFINITY};
  float lrun[4] = {0.f, 0.f, 0.f, 0.f};
  const f32x4 zero = {0.f, 0.f, 0.f, 0.f};
  f32x4 oacc[16];
#pragma unroll
  for (int i = 0; i < 16; ++i) oacc[i] = zero;

  const int wbase = (t & ~63);

#define STAGE(KT_, BUF_)                                                        \
  {                                                                             \
    _Pragma("unroll")                                                           \
    for (int i_ = 0; i_ < 4; ++i_) {                                            \
      const int idx_ = t + i_ * 512;                                           \
      const int row_ = idx_ >> 5;                                              \
      const int cb_ = (idx_ & 31) << 4;                                        \
      const int scb_ = cb_ ^ ((row_ & 7) << 4);                                \
      gload_lds16(kTb + ((size_t)((KT_) + row_)) * CH + (scb_ >> 1),           \
                  smem + (BUF_)*32768 + ((wbase + i_ * 512) << 4));            \
    }                                                                           \
    _Pragma("unroll")                                                           \
    for (int i_ = 0; i_ < 4; ++i_) {                                            \
      const int idx_ = t + i_ * 512;                                           \
      const int row_ = idx_ >> 3;                                              \
      const int cb_ = (idx_ & 7) << 4;                                         \
      const int scb_ = cb_ ^ ((row_ & 7) << 4);                                \
      gload_lds16(vNb + (size_t)row_ * NSP + (KT_) + (scb_ >> 1),              \
                  smem + 65536 + (BUF_)*32768 + ((wbase + i_ * 512) << 4));    \
    }                                                                           \
  }

  STAGE(0, 0);
  __syncthreads();

  for (int tt = 0; tt < NSP / 64; ++tt) {
    const int cur = tt & 1;
    if (tt + 1 < NSP / 64) STAGE((tt + 1) * 64, cur ^ 1);

    // ---- S = Q K^T for own m-half (rows wip*32..+32) ----
    f32x4 s[2] = {zero, zero};
    __builtin_amdgcn_s_setprio(1);
#pragma unroll
    for (int ks = 0; ks < 8; ++ks) {
#pragma unroll
      for (int mt = 0; mt < 2; ++mt) {
        const int row = wip * 32 + mt * 16 + lo;
        const int cb = (ks * 64 + hi * 16) ^ ((row & 7) << 4);
        const bf16x8 kv = *(const bf16x8*)(smem + cur * 32768 + row * 512 + cb);
        s[mt] = __builtin_amdgcn_mfma_f32_16x16x32_bf16(qreg[ks], kv, s[mt], 0, 0, 0);
      }
    }
    __builtin_amdgcn_s_setprio(0);

    // ---- wave-local online softmax, defer-max (THR=8) ----
    float mx[4];
#pragma unroll
    for (int r = 0; r < 4; ++r) {
      float m_ = fmaxf(s[0][r], s[1][r]);
      m_ = fmaxf(m_, __shfl_xor(m_, 1));
      m_ = fmaxf(m_, __shfl_xor(m_, 2));
      m_ = fmaxf(m_, __shfl_xor(m_, 4));
      m_ = fmaxf(m_, __shfl_xor(m_, 8));
      mx[r] = m_;
    }
    const bool grow = (mx[0] > mrun[0] + 8.f) | (mx[1] > mrun[1] + 8.f) |
                      (mx[2] > mrun[2] + 8.f) | (mx[3] > mrun[3] + 8.f);
    if (__any(grow)) {
#pragma unroll
      for (int r = 0; r < 4; ++r) {
        const float mm = fmaxf(mx[r], mrun[r]);
        const float al = __expf(mrun[r] - mm);
        mrun[r] = mm;
        lrun[r] *= al;
#pragma unroll
        for (int ct = 0; ct < 16; ++ct) oacc[ct][r] *= al;
      }
    }
#pragma unroll
    for (int r = 0; r < 4; ++r) {
      const float mm = mrun[r];
      const float p0 = __expf(s[0][r] - mm);
      const float p1 = __expf(s[1][r] - mm);
      Psw[(hi * 4 + r) * 40 + lo] = (short)f2bf(p0);
      Psw[(hi * 4 + r) * 40 + 16 + lo] = (short)f2bf(p1);
      float ps = p0 + p1;
      ps += __shfl_xor(ps, 1);
      ps += __shfl_xor(ps, 2);
      ps += __shfl_xor(ps, 4);
      ps += __shfl_xor(ps, 8);
      lrun[r] += ps;
    }

    // ---- O += P V^T (full 256 c, k = own 32 m) ----
    const bf16x8 pa = *(const bf16x8*)&Psw[lo * 40 + hi * 8];
    __builtin_amdgcn_s_setprio(1);
#pragma unroll
    for (int ct = 0; ct < 16; ++ct) {
      const int c = ct * 16 + lo;
      const int cb = (wip * 64 + hi * 16) ^ ((c & 7) << 4);
      const bf16x8 vv = *(const bf16x8*)(smem + 65536 + cur * 32768 + c * 128 + cb);
      oacc[ct] = __builtin_amdgcn_mfma_f32_16x16x32_bf16(pa, vv, oacc[ct], 0, 0, 0);
    }
    __builtin_amdgcn_s_setprio(0);

    __syncthreads();   // loads for tt+1 drained (vmcnt 0) + all reads of cur done
  }

  // ---- epilogue: merge the pair's two (m,l,O) streams ----
  if (lo == 0) {
#pragma unroll
    for (int r = 0; r < 4; ++r) {
      sM[(pair * 2 + wip) * 16 + hi * 4 + r] = mrun[r];
      sL[(pair * 2 + wip) * 16 + hi * 4 + r] = lrun[r];
    }
  }
  __syncthreads();
  float e[4], ltot[4];
#pragma unroll
  for (int r = 0; r < 4; ++r) {
    const float mo = sM[(pair * 2 + (wip ^ 1)) * 16 + hi * 4 + r];
    const float lo_ = sL[(pair * 2 + (wip ^ 1)) * 16 + hi * 4 + r];
    const float mm = fmaxf(mrun[r], mo);
    e[r] = __expf(mrun[r] - mm);
    const float eo = __expf(mo - mm);
    ltot[r] = e[r] * lrun[r] + eo * lo_;
#pragma unroll
    for (int ct = 0; ct < 16; ++ct) oacc[ct][r] *= e[r];
  }
  float* Obuf = (float*)smem;   // [4][16][260] fp32, overlaps K/V buffers
  if (wip == 1) {
#pragma unroll
    for (int ct = 0; ct < 16; ++ct)
#pragma unroll
      for (int r = 0; r < 4; ++r)
        Obuf[(pair * 16 + hi * 4 + r) * 260 + ct * 16 + lo] = oacc[ct][r];
  }
  __syncthreads();
  if (wip == 0) {
#pragma unroll
    for (int r = 0; r < 4; ++r) {
      const float li = 1.f / ltot[r];
      const int n = qb + pair * 16 + hi * 4 + r;
#pragma unroll
      for (int ct = 0; ct < 16; ++ct) {
        const float v = (oacc[ct][r] + Obuf[(pair * 16 + hi * 4 + r) * 260 + ct * 16 + lo]) * li;
        oTb[((size_t)(b * NSP) + n) * CH + ct * 16 + lo] = f2bf(v);
      }
    }
  }
#undef STAGE
}

// ------- kernel 6: projection + residual, bf16 MFMA -------
__global__ __launch_bounds__(256) void proj_mfma_k(const unsigned short* __restrict__ pwb,
                                                   const unsigned short* __restrict__ oTb,
                                                   const float* __restrict__ proj_b,
                                                   const float* __restrict__ x,
                                                   float* __restrict__ out) {
  const int b = blockIdx.z, ob = blockIdx.y * 64, nb = blockIdx.x * 64;
  const int t = threadIdx.x;
  __shared__ short Ws[64][264];
  __shared__ short Os[64][264];
  for (int i = 0; i < 8; ++i) {
    const int idx = t + i * 256;
    const int row = idx >> 5, u = (idx & 31) << 3;
    *(float4*)&Ws[row][u] = *(const float4*)(pwb + ((size_t)(ob + row)) * CH + u);
    *(float4*)&Os[row][u] = *(const float4*)(oTb + ((size_t)(b * NSP) + nb + row) * CH + u);
  }
  __syncthreads();
  const int lane = t & 63, wave = t >> 6, lo = lane & 15, hi = lane >> 4;
  const f32x4 zero = {0.f, 0.f, 0.f, 0.f};
  f32x4 acc[4] = {zero, zero, zero, zero};
#pragma unroll
  for (int ks = 0; ks < 8; ++ks) {
    const bf16x8 a = *(const bf16x8*)&Ws[wave * 16 + lo][ks * 32 + hi * 8];
#pragma unroll
    for (int nt = 0; nt < 4; ++nt) {
      const bf16x8 ov = *(const bf16x8*)&Os[nt * 16 + lo][ks * 32 + hi * 8];
      acc[nt] = __builtin_amdgcn_mfma_f32_16x16x32_bf16(a, ov, acc[nt], 0, 0, 0);
    }
  }
#pragma unroll
  for (int nt = 0; nt < 4; ++nt) {
#pragma unroll
    for (int r = 0; r < 4; ++r) {
      const int o = ob + wave * 16 + hi * 4 + r;
      const int n = nb + nt * 16 + lo;
      const size_t off = ((size_t)(b * CH + o)) * NSP + n;
      out[off] = acc[nt][r] + proj_b[o] + x[off];
    }
  }
}

extern "C" void kernel_launch(void* const* d_in, const int* in_sizes, int n_in,
                              void* d_out, int out_size, void* d_ws, size_t ws_size,
                              hipStream_t stream) {
  const float* x      = (const float*)d_in[0];
  const float* gn_w   = (const float*)d_in[1];
  const float* gn_b   = (const float*)d_in[2];
  const float* qkv_w  = (const float*)d_in[3];
  const float* qkv_b  = (const float*)d_in[4];
  const float* proj_w = (const float*)d_in[5];
  const float* proj_b = (const float*)d_in[6];
  float* out = (float*)d_out;

  char* w = (char*)d_ws;
  unsigned short* qT  = (unsigned short*)w; w += (size_t)BATCH * NSP * CH * 2;
  unsigned short* kT  = (unsigned short*)w; w += (size_t)BATCH * NSP * CH * 2;
  unsigned short* vN  = (unsigned short*)w; w += (size_t)BATCH * NSP * CH * 2;
  unsigned short* xbT = (unsigned short*)w; w += (size_t)BATCH * NSP * CH * 2;
  unsigned short* oTb = (unsigned short*)w; w += (size_t)BATCH * NSP * CH * 2;
  unsigned short* wb  = (unsigned short*)w; w += (size_t)3 * CH * CH * 2;
  unsigned short* pwb = (unsigned short*)w; w += (size_t)CH * CH * 2;
  float* gpart  = (float*)w; w += 512 * 4;
  float* ascale = (float*)w; w += BATCH * CH * 4;
  float* bias2  = (float*)w; w += BATCH * 3 * CH * 4;

  gn_part_k<<<256, 256, 0, stream>>>(x, gpart);
  fold_k<<<BATCH, 256, 0, stream>>>(gn_w, gn_b, qkv_w, qkv_b, proj_w, gpart,
                                    ascale, bias2, wb, pwb);
  xt_k<<<dim3(NSP / 64, CH / 64, BATCH), 256, 0, stream>>>(x, ascale, xbT);
  qkv_mfma_k<<<dim3(NSP / 64, 3 * CH / 64, BATCH), 256, 0, stream>>>(wb, xbT, bias2, qT, kT, vN);
  attn_mfma_k<<<256, 512, 0, stream>>>(qT, kT, vN, oTb);
  proj_mfma_k<<<dim3(NSP / 64, CH / 64, BATCH), 256, 0, stream>>>(pwb, oTb, proj_b, x, out);
}

// Round 10
// 302.893 us; speedup vs baseline: 2.0042x; 1.0919x over previous
//
#include <hip/hip_runtime.h>
#include <math.h>

// Round 10 (= round 7/8/9 resubmit; bench never ran — acquisition timeouts):
// attn v4 — 32x32x16 MFMA, swapped QK^T (S^T = K·Q) so softmax is lane-local
// (1 shfl), P kept in registers (cross-half shfl exchange, no P LDS), K/V LDS
// dbuf via global_load_lds with pre-swizzled sources, 4 waves = 2 qg x 2 mh,
// KT=64, 1 barrier/tile, defer-max, setprio, XCD swizzle. Others unchanged.

#define BATCH 4
#define CH 256
#define NSP 4096
#define NGRP 8
#define CPG 32

typedef __attribute__((ext_vector_type(8))) short bf16x8;
typedef __attribute__((ext_vector_type(4))) float f32x4;
typedef __attribute__((ext_vector_type(16))) float f32x16;

__device__ __forceinline__ unsigned short f2bf(float f) {
  union { float f; unsigned u; } v; v.f = f;
  unsigned r = v.u + 0x7FFF + ((v.u >> 16) & 1);   // RNE
  return (unsigned short)(r >> 16);
}

__device__ __forceinline__ unsigned pk2bf(float a, float b) {
  return (unsigned)f2bf(a) | ((unsigned)f2bf(b) << 16);
}

__device__ __forceinline__ void gload_lds16(const void* g, void* l) {
  __builtin_amdgcn_global_load_lds(
      (const __attribute__((address_space(1))) unsigned int*)g,
      (__attribute__((address_space(3))) unsigned int*)l, 16, 0, 0);
}

// ---------------- kernel 1a: GroupNorm partial sums (256 blocks) ----------------
__global__ __launch_bounds__(256) void gn_part_k(const float* __restrict__ x,
                                                 float* __restrict__ gpart) {
  const int bid = blockIdx.x;          // bg*8 + slice
  const int bg = bid >> 3, sl = bid & 7;
  const float4* p = (const float4*)(x + (size_t)bg * CPG * NSP + (size_t)sl * (CPG * NSP / 8));
  const int t = threadIdx.x;
  float s1 = 0.f, s2 = 0.f;
#pragma unroll
  for (int i = 0; i < 16; ++i) {
    float4 v = p[t + i * 256];
    s1 += v.x + v.y + v.z + v.w;
    s2 += v.x * v.x + v.y * v.y + v.z * v.z + v.w * v.w;
  }
  __shared__ float r1[256], r2[256];
  r1[t] = s1; r2[t] = s2;
  __syncthreads();
  for (int off = 128; off > 0; off >>= 1) {
    if (t < off) { r1[t] += r1[t + off]; r2[t] += r2[t + off]; }
    __syncthreads();
  }
  if (t == 0) { gpart[bid * 2] = r1[0]; gpart[bid * 2 + 1] = r2[0]; }
}

// ------- kernel 2: finalize stats, fold GN affine, convert weights -------
__global__ __launch_bounds__(256) void fold_k(const float* __restrict__ gn_w,
                                              const float* __restrict__ gn_b,
                                              const float* __restrict__ qkv_w,
                                              const float* __restrict__ qkv_b,
                                              const float* __restrict__ proj_w,
                                              const float* __restrict__ gpart,
                                              float* __restrict__ ascale,
                                              float* __restrict__ bias2,
                                              unsigned short* __restrict__ wb,
                                              unsigned short* __restrict__ pwb) {
  const int b = blockIdx.x;
  const int t = threadIdx.x;
  __shared__ float bb[CH];
  {
    const int c = t;
    const int g = c >> 5;
    float s1 = 0.f, s2 = 0.f;
#pragma unroll
    for (int s = 0; s < 8; ++s) {
      s1 += gpart[((b * NGRP + g) * 8 + s) * 2];
      s2 += gpart[((b * NGRP + g) * 8 + s) * 2 + 1];
    }
    const float inv = 1.f / (float)(CPG * NSP);
    const float mean = s1 * inv;
    const float var = s2 * inv - mean * mean;
    const float rstd = rsqrtf(var + 1e-5f);
    const float a = rstd * gn_w[c];
    ascale[b * CH + c] = a;
    bb[c] = gn_b[c] - mean * a;
  }
  __syncthreads();
  for (int o = t; o < 3 * CH; o += 256) {
    const float* wrow = qkv_w + (size_t)o * CH;
    float acc = qkv_b[o];
    for (int c = 0; c < CH; ++c) acc += wrow[c] * bb[c];
    if (o < CH) acc *= 0.0625f;
    bias2[b * 3 * CH + o] = acc;
  }
  for (int idx = t; idx < 192 * CH; idx += 256) {
    const int row = b * 192 + (idx >> 8);
    const int c = idx & 255;
    float w = qkv_w[(size_t)row * CH + c];
    if (row < CH) w *= 0.0625f;
    wb[(size_t)row * CH + c] = f2bf(w);
  }
  for (int idx = t; idx < 64 * CH; idx += 256) {
    const int row = b * 64 + (idx >> 8);
    const int c = idx & 255;
    pwb[(size_t)row * CH + c] = f2bf(proj_w[(size_t)row * CH + c]);
  }
}

// ------- kernel 3: x -> xbT[b][n][c] = bf16(x * ascale)  (transpose) -------
__global__ __launch_bounds__(256) void xt_k(const float* __restrict__ x,
                                            const float* __restrict__ ascale,
                                            unsigned short* __restrict__ xbT) {
  const int b = blockIdx.z, cb = blockIdx.y * 64, nb = blockIdx.x * 64;
  const int t = threadIdx.x;
  __shared__ float Ls[64][68];
  for (int i = 0; i < 4; ++i) {
    const int idx = t + i * 256;
    const int c = idx >> 4, n4 = (idx & 15) << 2;
    const float a = ascale[b * CH + cb + c];
    const float4 v = *(const float4*)(x + ((size_t)(b * CH + cb + c)) * NSP + nb + n4);
    Ls[c][n4] = v.x * a; Ls[c][n4 + 1] = v.y * a;
    Ls[c][n4 + 2] = v.z * a; Ls[c][n4 + 3] = v.w * a;
  }
  __syncthreads();
  {
    const int n = t >> 2, cg = (t & 3) << 4;
    unsigned int pk[8];
#pragma unroll
    for (int j = 0; j < 8; ++j) {
      const unsigned short l16 = f2bf(Ls[cg + 2 * j][n]);
      const unsigned short h16 = f2bf(Ls[cg + 2 * j + 1][n]);
      pk[j] = (unsigned)l16 | ((unsigned)h16 << 16);
    }
    unsigned short* dst = xbT + ((size_t)(b * NSP) + nb + n) * CH + cb + cg;
    *(uint4*)dst = *(uint4*)&pk[0];
    *(uint4*)(dst + 8) = *(uint4*)&pk[4];
  }
}

// ------- kernel 4: QKV GEMM, bf16 MFMA -------
__global__ __launch_bounds__(256) void qkv_mfma_k(const unsigned short* __restrict__ wb,
                                                  const unsigned short* __restrict__ xbT,
                                                  const float* __restrict__ bias2,
                                                  unsigned short* __restrict__ qT,
                                                  unsigned short* __restrict__ kT,
                                                  unsigned short* __restrict__ vN) {
  const int b = blockIdx.z, ob = blockIdx.y * 64, nb = blockIdx.x * 64;
  const int t = threadIdx.x;
  __shared__ short Ws[64][264];
  __shared__ short Xs[64][264];
  for (int i = 0; i < 8; ++i) {
    const int idx = t + i * 256;
    const int row = idx >> 5, u = (idx & 31) << 3;
    *(float4*)&Ws[row][u] = *(const float4*)(wb + ((size_t)(ob + row)) * CH + u);
    *(float4*)&Xs[row][u] = *(const float4*)(xbT + ((size_t)(b * NSP) + nb + row) * CH + u);
  }
  __syncthreads();
  const int lane = t & 63, wave = t >> 6, lo = lane & 15, hi = lane >> 4;
  const f32x4 zero = {0.f, 0.f, 0.f, 0.f};
  f32x4 acc[4] = {zero, zero, zero, zero};
#pragma unroll
  for (int ks = 0; ks < 8; ++ks) {
    const bf16x8 a = *(const bf16x8*)&Ws[wave * 16 + lo][ks * 32 + hi * 8];
#pragma unroll
    for (int nt = 0; nt < 4; ++nt) {
      const bf16x8 xv = *(const bf16x8*)&Xs[nt * 16 + lo][ks * 32 + hi * 8];
      acc[nt] = __builtin_amdgcn_mfma_f32_16x16x32_bf16(a, xv, acc[nt], 0, 0, 0);
    }
  }
#pragma unroll
  for (int nt = 0; nt < 4; ++nt) {
#pragma unroll
    for (int r = 0; r < 4; ++r) {
      const int o = ob + wave * 16 + hi * 4 + r;
      const int n = nb + nt * 16 + lo;
      const float v = acc[nt][r] + bias2[b * 3 * CH + o];
      if (o < CH)            qT[((size_t)(b * NSP) + n) * CH + o] = f2bf(v);
      else if (o < 2 * CH)   kT[((size_t)(b * NSP) + n) * CH + (o - CH)] = f2bf(v);
      else                   vN[((size_t)(b * CH) + (o - 2 * CH)) * NSP + n] = f2bf(v);
    }
  }
}

// ------- kernel 5: flash attention v4 -------
// 256 thr / 4 waves = 2 qg (32q) x 2 mh (32m). S^T = K·Q via 32x32x16 MFMA:
// lane owns one q-column -> softmax lane-local (+1 shfl_xor(32)); P stays in
// registers, PV B-frags built via 4 cross-half shfls. K [64][512B] and
// V [128][256B] (2 c-rows packed) LDS dbuf, XOR-swizzled (pre-swizzled src).
__global__ __launch_bounds__(256, 1) void attn_mfma_k(const unsigned short* __restrict__ qT,
                                                      const unsigned short* __restrict__ kT,
                                                      const unsigned short* __restrict__ vN,
                                                      unsigned short* __restrict__ oTb) {
  const int bid = blockIdx.x;
  const int L = (bid & 7) * 32 + (bid >> 3);   // XCD swizzle
  const int b = L >> 6;
  const int qb = (L & 63) * 64;

  const int t = threadIdx.x;
  const int wid = t >> 6, lane = t & 63;
  const int cl = lane & 31, h = lane >> 5;
  const int qg = wid >> 1, mh = wid & 1;

  // smem: [0,65536) K dbuf [2][64][512B] ; [65536,131072) V dbuf [2][128][256B]
  //       [131072,131584) sM [2qg][2mh][32] ; [131584,132096) sL
  __shared__ __align__(16) char smem[132096];
  float* sM = (float*)(smem + 131072);
  float* sL = (float*)(smem + 131584);

  const unsigned short* kTb = kT + (size_t)b * NSP * CH;
  const unsigned short* vNb = vN + (size_t)b * CH * NSP;

  // Q B-fragments: col q = cl, k-elems c = ks*16 + h*8 + j
  bf16x8 qreg[16];
  {
    const unsigned short* qp = qT + ((size_t)(b * NSP) + qb + qg * 32 + cl) * CH + h * 8;
#pragma unroll
    for (int ks = 0; ks < 16; ++ks) qreg[ks] = *(const bf16x8*)(qp + ks * 16);
  }

  const f32x16 z16 = {0.f,0.f,0.f,0.f,0.f,0.f,0.f,0.f,0.f,0.f,0.f,0.f,0.f,0.f,0.f,0.f};
  float mrun = -INFINITY, lrun = 0.f;
  f32x16 oacc[8];
#pragma unroll
  for (int i = 0; i < 8; ++i) oacc[i] = z16;

  const int wbase = (t & ~63);
  const int rowbase = (mh * 32 + cl) * 512;     // K row byte base
  const int rswz = (cl & 7) << 4;               // K row swizzle ((row&7)<<4)

#define STAGE(KT_, BUF_)                                                        \
  {                                                                             \
    _Pragma("unroll")                                                           \
    for (int i_ = 0; i_ < 8; ++i_) {                                            \
      const int idx_ = t + i_ * 256;                                            \
      const int row_ = idx_ >> 5;                                               \
      const int cby_ = (idx_ & 31) << 4;                                        \
      const int scb_ = cby_ ^ ((row_ & 7) << 4);                                \
      gload_lds16(kTb + ((size_t)((KT_) + row_)) * CH + (scb_ >> 1),            \
                  smem + (BUF_) * 32768 + ((wbase + i_ * 256) << 4));           \
    }                                                                           \
    _Pragma("unroll")                                                           \
    for (int i_ = 0; i_ < 8; ++i_) {                                            \
      const int idx_ = t + i_ * 256;                                            \
      const int rv_ = idx_ >> 4;                                                \
      const int inner_ = (idx_ & 15) << 4;                                      \
      const int ch_ = rv_ * 2 + (inner_ >> 7);                                  \
      const int mby_ = (inner_ & 127) ^ ((rv_ & 7) << 4);                       \
      gload_lds16(vNb + (size_t)ch_ * NSP + (KT_) + (mby_ >> 1),                \
                  smem + 65536 + (BUF_) * 32768 + ((wbase + i_ * 256) << 4));   \
    }                                                                           \
  }

  STAGE(0, 0);
  __syncthreads();

  for (int tt = 0; tt < NSP / 64; ++tt) {
    const int cur = tt & 1;
    const char* Kb = smem + cur * 32768 + rowbase;
    const char* Vb = smem + 65536 + cur * 32768;

    // ---- S^T = K·Q : rows m (this wave's 32), cols q ----
    f32x16 s0 = z16, s1 = z16;
    __builtin_amdgcn_s_setprio(1);
#pragma unroll
    for (int ks = 0; ks < 16; ks += 2) {
      const bf16x8 a0 = *(const bf16x8*)(Kb + ((ks * 32 + h * 16) ^ rswz));
      const bf16x8 a1 = *(const bf16x8*)(Kb + (((ks + 1) * 32 + h * 16) ^ rswz));
      s0 = __builtin_amdgcn_mfma_f32_32x32x16_bf16(a0, qreg[ks], s0, 0, 0, 0);
      s1 = __builtin_amdgcn_mfma_f32_32x32x16_bf16(a1, qreg[ks + 1], s1, 0, 0, 0);
    }
    __builtin_amdgcn_s_setprio(0);
    const f32x16 s = s0 + s1;

    // ---- lane-local online softmax (lane owns q = cl; m split across h) ----
    float mx = s[0];
#pragma unroll
    for (int r = 1; r < 16; ++r) mx = fmaxf(mx, s[r]);
    mx = fmaxf(mx, __shfl_xor(mx, 32));
    if (__any(mx > mrun + 8.f)) {          // defer-max THR=8
      const float mm = fmaxf(mx, mrun);
      const float al = __expf(mrun - mm);
      mrun = mm;
      lrun *= al;
#pragma unroll
      for (int cf = 0; cf < 8; ++cf) oacc[cf] *= al;
    }
    float p[16];
    float ps = 0.f;
#pragma unroll
    for (int r = 0; r < 16; ++r) { p[r] = __expf(s[r] - mrun); ps += p[r]; }
    ps += __shfl_xor(ps, 32);
    lrun += ps;

    // pack P to bf16 pairs; lane holds m = (r&3)+8*(r>>2)+4h
    const unsigned w0 = pk2bf(p[0], p[1]),   w1 = pk2bf(p[2], p[3]);
    const unsigned w2 = pk2bf(p[4], p[5]),   w3 = pk2bf(p[6], p[7]);
    const unsigned w4 = pk2bf(p[8], p[9]),   w5 = pk2bf(p[10], p[11]);
    const unsigned w6 = pk2bf(p[12], p[13]), w7 = pk2bf(p[14], p[15]);
    // cross-half exchange to assemble B-frags (k = m = ks2*16 + h*8 + j)
    const unsigned e0 = __shfl_xor(h ? w0 : w2, 32);
    const unsigned e1 = __shfl_xor(h ? w1 : w3, 32);
    const unsigned e2 = __shfl_xor(h ? w4 : w6, 32);
    const unsigned e3 = __shfl_xor(h ? w5 : w7, 32);
    union { bf16x8 v; unsigned u[4]; } B0, B1;
    B0.u[0] = h ? e0 : w0;  B0.u[1] = h ? e1 : w1;
    B0.u[2] = h ? w2 : e0;  B0.u[3] = h ? w3 : e1;
    B1.u[0] = h ? e2 : w4;  B1.u[1] = h ? e3 : w5;
    B1.u[2] = h ? w6 : e2;  B1.u[3] = h ? w7 : e3;

    if (tt + 1 < NSP / 64) STAGE((tt + 1) * 64, cur ^ 1);

    // ---- O^T += V^T · P^T : rows c, cols q, k = this wave's 32 m ----
    __builtin_amdgcn_s_setprio(1);
#pragma unroll
    for (int cf = 0; cf < 8; ++cf) {
      const int c = cf * 32 + cl;
      const char* vrow = Vb + (c >> 1) * 256 + (c & 1) * 128;
      const int sw = ((c >> 1) & 7) << 4;
      const bf16x8 va0 = *(const bf16x8*)(vrow + ((mh * 64 + h * 16) ^ sw));
      const bf16x8 va1 = *(const bf16x8*)(vrow + ((mh * 64 + 32 + h * 16) ^ sw));
      oacc[cf] = __builtin_amdgcn_mfma_f32_32x32x16_bf16(va0, B0.v, oacc[cf], 0, 0, 0);
      oacc[cf] = __builtin_amdgcn_mfma_f32_32x32x16_bf16(va1, B1.v, oacc[cf], 0, 0, 0);
    }
    __builtin_amdgcn_s_setprio(0);

    __syncthreads();   // staged tile drained (vmcnt 0) + all LDS reads of cur done
  }

  // ---- epilogue: merge the two mh streams per qg ----
  if (h == 0) {
    sM[(qg * 2 + mh) * 32 + cl] = mrun;
    sL[(qg * 2 + mh) * 32 + cl] = lrun;
  }
  __syncthreads();
  const float mo = sM[(qg * 2 + (mh ^ 1)) * 32 + cl];
  const float lo_ = sL[(qg * 2 + (mh ^ 1)) * 32 + cl];
  const float mm2 = fmaxf(mrun, mo);
  const float e = __expf(mrun - mm2);
  const float ltot = e * lrun + __expf(mo - mm2) * lo_;
#pragma unroll
  for (int cf = 0; cf < 8; ++cf) oacc[cf] *= e;

  float* Obuf = (float*)smem;   // [2qg][32 q][264 c] f32 (reuses K/V region)
  float* Ob = Obuf + (qg * 32 + cl) * 264;
  if (mh == 1) {
#pragma unroll
    for (int cf = 0; cf < 8; ++cf)
#pragma unroll
      for (int r = 0; r < 16; ++r)
        Ob[cf * 32 + (r & 3) + 8 * (r >> 2) + 4 * h] = oacc[cf][r];
  }
  __syncthreads();
  if (mh == 0) {
    const float inv = 1.f / ltot;
    unsigned short* dst = oTb + ((size_t)(b * NSP) + qb + qg * 32 + cl) * CH;
#pragma unroll
    for (int cf = 0; cf < 8; ++cf) {
#pragma unroll
      for (int g = 0; g < 4; ++g) {
        const int c0 = cf * 32 + 8 * g + 4 * h;
        const float v0 = (oacc[cf][4 * g + 0] + Ob[c0 + 0]) * inv;
        const float v1 = (oacc[cf][4 * g + 1] + Ob[c0 + 1]) * inv;
        const float v2 = (oacc[cf][4 * g + 2] + Ob[c0 + 2]) * inv;
        const float v3 = (oacc[cf][4 * g + 3] + Ob[c0 + 3]) * inv;
        uint2 pkd;
        pkd.x = pk2bf(v0, v1);
        pkd.y = pk2bf(v2, v3);
        *(uint2*)(dst + c0) = pkd;
      }
    }
  }
#undef STAGE
}

// ------- kernel 6: projection + residual, bf16 MFMA -------
__global__ __launch_bounds__(256) void proj_mfma_k(const unsigned short* __restrict__ pwb,
                                                   const unsigned short* __restrict__ oTb,
                                                   const float* __restrict__ proj_b,
                                                   const float* __restrict__ x,
                                                   float* __restrict__ out) {
  const int b = blockIdx.z, ob = blockIdx.y * 64, nb = blockIdx.x * 64;
  const int t = threadIdx.x;
  __shared__ short Ws[64][264];
  __shared__ short Os[64][264];
  for (int i = 0; i < 8; ++i) {
    const int idx = t + i * 256;
    const int row = idx >> 5, u = (idx & 31) << 3;
    *(float4*)&Ws[row][u] = *(const float4*)(pwb + ((size_t)(ob + row)) * CH + u);
    *(float4*)&Os[row][u] = *(const float4*)(oTb + ((size_t)(b * NSP) + nb + row) * CH + u);
  }
  __syncthreads();
  const int lane = t & 63, wave = t >> 6, lo = lane & 15, hi = lane >> 4;
  const f32x4 zero = {0.f, 0.f, 0.f, 0.f};
  f32x4 acc[4] = {zero, zero, zero, zero};
#pragma unroll
  for (int ks = 0; ks < 8; ++ks) {
    const bf16x8 a = *(const bf16x8*)&Ws[wave * 16 + lo][ks * 32 + hi * 8];
#pragma unroll
    for (int nt = 0; nt < 4; ++nt) {
      const bf16x8 ov = *(const bf16x8*)&Os[nt * 16 + lo][ks * 32 + hi * 8];
      acc[nt] = __builtin_amdgcn_mfma_f32_16x16x32_bf16(a, ov, acc[nt], 0, 0, 0);
    }
  }
#pragma unroll
  for (int nt = 0; nt < 4; ++nt) {
#pragma unroll
    for (int r = 0; r < 4; ++r) {
      const int o = ob + wave * 16 + hi * 4 + r;
      const int n = nb + nt * 16 + lo;
      const size_t off = ((size_t)(b * CH + o)) * NSP + n;
      out[off] = acc[nt][r] + proj_b[o] + x[off];
    }
  }
}

extern "C" void kernel_launch(void* const* d_in, const int* in_sizes, int n_in,
                              void* d_out, int out_size, void* d_ws, size_t ws_size,
                              hipStream_t stream) {
  const float* x      = (const float*)d_in[0];
  const float* gn_w   = (const float*)d_in[1];
  const float* gn_b   = (const float*)d_in[2];
  const float* qkv_w  = (const float*)d_in[3];
  const float* qkv_b  = (const float*)d_in[4];
  const float* proj_w = (const float*)d_in[5];
  const float* proj_b = (const float*)d_in[6];
  float* out = (float*)d_out;

  char* w = (char*)d_ws;
  unsigned short* qT  = (unsigned short*)w; w += (size_t)BATCH * NSP * CH * 2;
  unsigned short* kT  = (unsigned short*)w; w += (size_t)BATCH * NSP * CH * 2;
  unsigned short* vN  = (unsigned short*)w; w += (size_t)BATCH * NSP * CH * 2;
  unsigned short* xbT = (unsigned short*)w; w += (size_t)BATCH * NSP * CH * 2;
  unsigned short* oTb = (unsigned short*)w; w += (size_t)BATCH * NSP * CH * 2;
  unsigned short* wb  = (unsigned short*)w; w += (size_t)3 * CH * CH * 2;
  unsigned short* pwb = (unsigned short*)w; w += (size_t)CH * CH * 2;
  float* gpart  = (float*)w; w += 512 * 4;
  float* ascale = (float*)w; w += BATCH * CH * 4;
  float* bias2  = (float*)w; w += BATCH * 3 * CH * 4;

  gn_part_k<<<256, 256, 0, stream>>>(x, gpart);
  fold_k<<<BATCH, 256, 0, stream>>>(gn_w, gn_b, qkv_w, qkv_b, proj_w, gpart,
                                    ascale, bias2, wb, pwb);
  xt_k<<<dim3(NSP / 64, CH / 64, BATCH), 256, 0, stream>>>(x, ascale, xbT);
  qkv_mfma_k<<<dim3(NSP / 64, 3 * CH / 64, BATCH), 256, 0, stream>>>(wb, xbT, bias2, qT, kT, vN);
  attn_mfma_k<<<256, 256, 0, stream>>>(qT, kT, vN, oTb);
  proj_mfma_k<<<dim3(NSP / 64, CH / 64, BATCH), 256, 0, stream>>>(pwb, oTb, proj_b, x, out);
}